// Round 2
// baseline (8985.519 us; speedup 1.0000x reference)
//
#include <hip/hip_runtime.h>
#include <hip/hip_bf16.h>
#include <math.h>

// ---------------- constants (fixed by setup_inputs) ----------------
constexpr int B   = 128;   // batch
constexpr int N1  = 32;    // agents (1 ego + 31 veh)
constexpr int HH  = 20;    // history steps (T-2)
constexpr int L   = 64;    // lanes
constexpr int PTS = 10;    // points per lane
constexpr int F   = 128;   // feature size
constexpr int LF  = 64;    // lane feature
constexpr int NH  = 8;     // heads
constexpr int HD  = 16;    // head dim
constexpr int KVN = 96;    // kv tokens = 32 agents + 64 lanes
constexpr int G4  = 512;   // 4*F lstm gates
constexpr int NP  = 6;     // num preds
constexpr int P6  = 36;    // NP*6
constexpr int LEN = 30;    // len_pred

__device__ __forceinline__ float sigmoidf(float x) { return 1.f / (1.f + expf(-x)); }

// ---------------- one-time kernels ----------------

// lane MLP -> lane tokens, written into kvbuf rows 32..95 of each batch
__global__ void k_lane_tok(const float* __restrict__ lane_input,
                           const float* __restrict__ w1, const float* __restrict__ b1,
                           const float* __restrict__ w2, const float* __restrict__ b2,
                           const float* __restrict__ to_f,
                           float* __restrict__ kvbuf) {
    int bl = blockIdx.x; int b = bl / L, l = bl % L;
    int tid = threadIdx.x; // 64 threads
    __shared__ float h1[PTS][LF];
    __shared__ float m[LF];
    const float* xin = lane_input + ((size_t)(b * L + l) * PTS) * 2;
    float w10 = w1[tid], w11 = w1[LF + tid], bb1 = b1[tid];
    for (int p = 0; p < PTS; ++p) {
        float v = xin[p * 2] * w10 + xin[p * 2 + 1] * w11 + bb1;
        h1[p][tid] = fmaxf(v, 0.f);
    }
    __syncthreads();
    float acc = 0.f;
    for (int p = 0; p < PTS; ++p) {
        float s = b2[tid];
        for (int h = 0; h < LF; ++h) s += h1[p][h] * w2[h * LF + tid];
        acc += fmaxf(s, 0.f);
    }
    m[tid] = acc * (1.f / PTS);
    __syncthreads();
    float* outp = kvbuf + ((size_t)(b * KVN) + 32 + l) * F;
    for (int f = tid; f < F; f += LF) {
        float s = 0.f;
        for (int j = 0; j < LF; ++j) s += m[j] * to_f[j * F + f];
        outp[f] = s;
    }
}

// lane K/V: project constant lane tokens once. 8 rows per block.
__global__ void k_lane_kv(const float* __restrict__ kvbuf,
                          const float* __restrict__ wk, const float* __restrict__ wv,
                          float* __restrict__ kb, float* __restrict__ vb) {
    int g = blockIdx.x & 7, b = blockIdx.x >> 3;
    int n0 = 32 + g * 8;
    int tid = threadIdx.x; // 256
    int j = tid & 127, rh = tid >> 7; // rh 0..1
    __shared__ float tok[8][F];
    for (int i = tid; i < 8 * F; i += 256) {
        int r = i >> 7, c = i & 127;
        tok[r][c] = kvbuf[((size_t)b * KVN + n0 + r) * F + c];
    }
    __syncthreads();
    float ak[4] = {0, 0, 0, 0}, av[4] = {0, 0, 0, 0};
    int r0 = rh * 4;
    for (int k2 = 0; k2 < F; ++k2) {
        float wkv = wk[k2 * F + j], wvv = wv[k2 * F + j];
#pragma unroll
        for (int r = 0; r < 4; ++r) {
            float x = tok[r0 + r][k2];
            ak[r] += x * wkv; av[r] += x * wvv;
        }
    }
#pragma unroll
    for (int r = 0; r < 4; ++r) {
        int n = n0 + r0 + r;
        kb[((size_t)b * KVN + n) * F + j] = ak[r];
        vb[((size_t)b * KVN + n) * F + j] = av[r];
    }
}

// cumulative positions over history + init pred_pos from final position
__global__ void k_hist_pos(const float* __restrict__ input,
                           const float* __restrict__ init_pos,
                           float* __restrict__ hist_pos,
                           float* __restrict__ pred_pos) {
    int idx = blockIdx.x * blockDim.x + threadIdx.x;
    if (idx >= B * N1) return;
    float px = init_pos[idx * 2], py = init_pos[idx * 2 + 1];
    int b = idx / N1, n = idx % N1;
    for (int t = 0; t < HH; ++t) {
        const float* ip = input + ((size_t)(t * B + b) * N1 + n) * 2;
        float dl = ip[0], yaw = ip[1];
        px += dl * cosf(yaw);
        py += dl * sinf(yaw);
        float* hp = hist_pos + ((size_t)(t * B + b) * N1 + n) * 2;
        hp[0] = px; hp[1] = py;
    }
#pragma unroll
    for (int p = 0; p < NP; ++p) {
        pred_pos[((size_t)idx * NP + p) * 2 + 0] = px;
        pred_pos[((size_t)idx * NP + p) * 2 + 1] = py;
    }
}

// transpose all 4 (G4,F) LSTM weights -> (F,G4) in one kernel
__global__ void k_transpose_all(const float* __restrict__ w0, const float* __restrict__ w1,
                                const float* __restrict__ w2, const float* __restrict__ w3,
                                float* __restrict__ wt) {
    int i = blockIdx.x * blockDim.x + threadIdx.x;
    if (i >= 4 * G4 * F) return;
    int m = i / (G4 * F), rem = i % (G4 * F);
    int j = rem / F, k2 = rem % F;
    const float* src = (m == 0) ? w0 : (m == 1) ? w1 : (m == 2) ? w2 : w3;
    wt[(size_t)m * G4 * F + (size_t)k2 * G4 + j] = src[rem];
}

// ---------------- per-step kernels ----------------

// Kernel A: build agent tokens (hist conv or pred h+pos) + q/k/v projections.
// grid B*4, block 256, 8 token rows per block.
__global__ void k_tok_qkv(const float* __restrict__ input, const float* __restrict__ hist_pos,
                          const float* __restrict__ h, const float* __restrict__ pred_pos,
                          const float* __restrict__ conv_w, const float* __restrict__ conv_b,
                          const float* __restrict__ pos_w, const float* __restrict__ pos_b,
                          const float* __restrict__ wq, const float* __restrict__ wk,
                          const float* __restrict__ wv,
                          float* __restrict__ kvbuf, float* __restrict__ qb,
                          float* __restrict__ kb, float* __restrict__ vb,
                          int mode, int t) {
    int g = blockIdx.x & 3, b = blockIdx.x >> 2;
    int n0 = g * 8;
    int tid = threadIdx.x;
    int j = tid & 127, rh = tid >> 7;
    __shared__ float tok[8][F];
    for (int i = tid; i < 8 * F; i += 256) {
        int r = i >> 7, c = i & 127;
        int n = n0 + r;
        float acc;
        if (mode == 0) {
            acc = conv_b[c];
#pragma unroll
            for (int kt = 0; kt < 3; ++kt) {
                const float* ip = input + ((size_t)((t + kt) * B + b) * N1 + n) * 2;
                acc += ip[0] * conv_w[(c * 2 + 0) * 3 + kt] + ip[1] * conv_w[(c * 2 + 1) * 3 + kt];
            }
            const float* hp = hist_pos + ((size_t)(t * B + b) * N1 + n) * 2;
            acc += hp[0] * pos_w[c] + hp[1] * pos_w[F + c] + pos_b[c];
        } else {
            const float* pp = pred_pos + ((size_t)(b * N1 + n)) * NP * 2;
            float mx = 0.f, my = 0.f;
#pragma unroll
            for (int p = 0; p < NP; ++p) { mx += pp[p * 2]; my += pp[p * 2 + 1]; }
            mx *= (1.f / NP); my *= (1.f / NP);
            acc = h[((size_t)b * N1 + n) * F + c] + mx * pos_w[c] + my * pos_w[F + c] + pos_b[c];
        }
        tok[r][c] = acc;
        kvbuf[((size_t)b * KVN + n) * F + c] = acc;
    }
    __syncthreads();
    float aq[4] = {0, 0, 0, 0}, ak[4] = {0, 0, 0, 0}, av[4] = {0, 0, 0, 0};
    int r0 = rh * 4;
    for (int k2 = 0; k2 < F; ++k2) {
        float wqv = wq[k2 * F + j], wkv = wk[k2 * F + j], wvv = wv[k2 * F + j];
#pragma unroll
        for (int r = 0; r < 4; ++r) {
            float x = tok[r0 + r][k2];
            aq[r] += x * wqv; ak[r] += x * wkv; av[r] += x * wvv;
        }
    }
#pragma unroll
    for (int r = 0; r < 4; ++r) {
        int n = n0 + r0 + r;
        qb[((size_t)b * N1 + n) * F + j]  = aq[r];
        kb[((size_t)b * KVN + n) * F + j] = ak[r];
        vb[((size_t)b * KVN + n) * F + j] = av[r];
    }
}

// Kernel B: attention (all heads) + out-proj + residual + layernorm. grid B, block 512.
__global__ void k_attn_proj_ln(const float* __restrict__ qb, const float* __restrict__ kb,
                               const float* __restrict__ vb, const float* __restrict__ kvbuf,
                               const float* __restrict__ mask_in, const float* __restrict__ lane_mask,
                               const float* __restrict__ wo,
                               const float* __restrict__ ln_ego_g, const float* __restrict__ ln_ego_b,
                               const float* __restrict__ ln_g, const float* __restrict__ ln_b,
                               float* __restrict__ xln) {
    int b = blockIdx.x;
    int tid = threadIdx.x; // 512
    __shared__ float qh[N1][HD];        // 2 KB
    __shared__ float kh[KVN][HD];       // 6 KB
    __shared__ float vh[KVN][HD];       // 6 KB
    __shared__ float sc[N1][KVN + 1];   // 12.1 KB (pad to break bank conflict)
    __shared__ float ao[N1][F];         // 16 KB
    __shared__ float xb[N1][F];         // 16 KB
    __shared__ float red[N1][2];

    for (int h = 0; h < NH; ++h) {
        // stage q,k,v head slices
        if (tid < N1 * HD) {
            int qr = tid >> 4, d = tid & 15;
            qh[qr][d] = qb[((size_t)b * N1 + qr) * F + h * HD + d];
        }
        for (int i = tid; i < KVN * HD; i += 512) {
            int kc = i >> 4, d = i & 15;
            kh[kc][d] = kb[((size_t)b * KVN + kc) * F + h * HD + d];
            vh[kc][d] = vb[((size_t)b * KVN + kc) * F + h * HD + d];
        }
        __syncthreads();
        // scores
        for (int i = tid; i < N1 * KVN; i += 512) {
            int qr = i / KVN, kc = i % KVN;
            float acc = 0.f;
#pragma unroll
            for (int d = 0; d < HD; ++d) acc += qh[qr][d] * kh[kc][d];
            float mval = (kc < N1) ? mask_in[b * N1 + kc] : lane_mask[b * L + (kc - N1)];
            sc[qr][kc] = (mval > 0.f) ? acc * 0.25f : -1e9f;
        }
        __syncthreads();
        // softmax per row
        if (tid < N1) {
            float mx = -1e30f;
            for (int kc = 0; kc < KVN; ++kc) mx = fmaxf(mx, sc[tid][kc]);
            float sum = 0.f;
            for (int kc = 0; kc < KVN; ++kc) { float e = expf(sc[tid][kc] - mx); sc[tid][kc] = e; sum += e; }
            float inv = 1.f / sum;
            for (int kc = 0; kc < KVN; ++kc) sc[tid][kc] *= inv;
        }
        __syncthreads();
        // PV
        if (tid < N1 * HD) {
            int qr = tid >> 4, d = tid & 15;
            float acc = 0.f;
            for (int kc = 0; kc < KVN; ++kc) acc += sc[qr][kc] * vh[kc][d];
            ao[qr][h * HD + d] = acc;
        }
        __syncthreads();
    }
    // out-proj + residual
    int j = tid & 127, rh = tid >> 7; // rh 0..3 -> 8 rows each
    float acc[8] = {0, 0, 0, 0, 0, 0, 0, 0};
    int r0 = rh * 8;
    for (int k2 = 0; k2 < F; ++k2) {
        float w = wo[k2 * F + j];
#pragma unroll
        for (int r = 0; r < 8; ++r) acc[r] += ao[r0 + r][k2] * w;
    }
#pragma unroll
    for (int r = 0; r < 8; ++r) {
        int n = r0 + r;
        xb[n][j] = kvbuf[((size_t)b * KVN + n) * F + j] + acc[r];
    }
    __syncthreads();
    // layernorm stats
    if (tid < N1) {
        float s1 = 0.f, s2 = 0.f;
        for (int c = 0; c < F; ++c) { float x = xb[tid][c]; s1 += x; s2 += x * x; }
        float mean = s1 * (1.f / F);
        float var = s2 * (1.f / F) - mean * mean;
        red[tid][0] = mean;
        red[tid][1] = rsqrtf(var + 1e-5f);
    }
    __syncthreads();
    for (int i = tid; i < N1 * F; i += 512) {
        int r = i >> 7, c = i & 127;
        const float* g  = (r == 0) ? ln_ego_g : ln_g;
        const float* bb = (r == 0) ? ln_ego_b : ln_b;
        xln[((size_t)b * N1 + r) * F + c] = (xb[r][c] - red[r][0]) * red[r][1] * g[c] + bb[c];
    }
}

// Kernel C: LSTM cell (16 batch rows/block) + (pred mode) output head + pos update + y.
// grid N1*8 = 256 blocks, block 512.
__global__ void k_lstm_pred(const float* __restrict__ xln,
                            const float* __restrict__ ego_wih_t, const float* __restrict__ ego_whh_t,
                            const float* __restrict__ ego_bih, const float* __restrict__ ego_bhh,
                            const float* __restrict__ veh_wih_t, const float* __restrict__ veh_whh_t,
                            const float* __restrict__ veh_bih, const float* __restrict__ veh_bhh,
                            float* __restrict__ h, float* __restrict__ c,
                            const float* __restrict__ out_ego_w, const float* __restrict__ out_ego_b,
                            const float* __restrict__ out_w, const float* __restrict__ out_b,
                            float* __restrict__ pred_pos, float* __restrict__ out,
                            int mode, int step) {
    int n = blockIdx.x >> 3, bg = blockIdx.x & 7;
    int b0 = bg * 16;
    int j = threadIdx.x; // 512
    const float *wih, *whh, *bih, *bhh;
    if (n == 0) { wih = ego_wih_t; whh = ego_whh_t; bih = ego_bih; bhh = ego_bhh; }
    else        { wih = veh_wih_t; whh = veh_whh_t; bih = veh_bih; bhh = veh_bhh; }
    __shared__ float xr[16][F];  // later reused to hold h2
    __shared__ float hr2[16][F];
    __shared__ float gs[16][G4];
    for (int i = j; i < 16 * F; i += 512) {
        int r = i >> 7, k2 = i & 127;
        size_t bn = (size_t)(b0 + r) * N1 + n;
        xr[r][k2]  = xln[bn * F + k2];
        hr2[r][k2] = h[bn * F + k2];
    }
    __syncthreads();
    float acc[16];
    float bsum = bih[j] + bhh[j];
#pragma unroll
    for (int r = 0; r < 16; ++r) acc[r] = bsum;
    for (int k2 = 0; k2 < F; ++k2) {
        float w1 = wih[(size_t)k2 * G4 + j];
        float w2 = whh[(size_t)k2 * G4 + j];
#pragma unroll
        for (int r = 0; r < 16; ++r) acc[r] += xr[r][k2] * w1 + hr2[r][k2] * w2;
    }
#pragma unroll
    for (int r = 0; r < 16; ++r) gs[r][j] = acc[r];
    __syncthreads();
    for (int i = j; i < 16 * F; i += 512) {
        int r = i >> 7, f = i & 127;
        size_t bn = (size_t)(b0 + r) * N1 + n;
        float ig = gs[r][f], fg = gs[r][F + f], gg = gs[r][2 * F + f], og = gs[r][3 * F + f];
        float cold = c[bn * F + f];
        float c2 = sigmoidf(fg) * cold + sigmoidf(ig) * tanhf(gg);
        float h2 = sigmoidf(og) * tanhf(c2);
        c[bn * F + f] = c2;
        h[bn * F + f] = h2;
        xr[r][f] = h2;   // stash for pred head
    }
    if (mode == 1) {
        const float* W  = (n == 0) ? out_ego_w : out_w;
        const float* bb = (n == 0) ? out_ego_b : out_b;
        __syncthreads();
        for (int i = j; i < 16 * P6; i += 512) {
            int r = i / P6, jj = i % P6;
            float a = bb[jj];
            for (int k2 = 0; k2 < F; ++k2) a += xr[r][k2] * W[k2 * P6 + jj];
            gs[r][jj] = a; // reuse gs as o36 store
        }
        __syncthreads();
        if (j < 16 * NP) {
            int r = j / NP, p = j % NP;
            size_t bn = (size_t)(b0 + r) * N1 + n;
            float dl = gs[r][p * 6 + 0], yaw = gs[r][p * 6 + 1];
            float* pp = pred_pos + (bn * NP + p) * 2;
            float px = pp[0] + dl * cosf(yaw);
            float py = pp[1] + dl * sinf(yaw);
            pp[0] = px; pp[1] = py;
            float* y = out + (size_t)step * B * N1 * P6 + (bn * NP + p) * 6;
            y[0] = px; y[1] = py;
            y[2] = gs[r][p * 6 + 2]; y[3] = gs[r][p * 6 + 3];
            y[4] = gs[r][p * 6 + 4]; y[5] = gs[r][p * 6 + 5];
        }
    }
}

// ---------------- launcher ----------------
extern "C" void kernel_launch(void* const* d_in, const int* in_sizes, int n_in,
                              void* d_out, int out_size, void* d_ws, size_t ws_size,
                              hipStream_t stream) {
    const float* input      = (const float*)d_in[0];
    const float* init_pos   = (const float*)d_in[1];
    const float* lane_input = (const float*)d_in[2];
    const float* mask_input = (const float*)d_in[3];
    const float* lane_mask  = (const float*)d_in[4];
    const float* conv_w     = (const float*)d_in[5];
    const float* conv_b     = (const float*)d_in[6];
    const float* pos_w      = (const float*)d_in[7];
    const float* pos_b      = (const float*)d_in[8];
    const float* lane_w1    = (const float*)d_in[9];
    const float* lane_b1    = (const float*)d_in[10];
    const float* lane_w2    = (const float*)d_in[11];
    const float* lane_b2    = (const float*)d_in[12];
    const float* lane_to_f  = (const float*)d_in[13];
    const float* wq         = (const float*)d_in[14];
    const float* wk         = (const float*)d_in[15];
    const float* wv         = (const float*)d_in[16];
    const float* wo         = (const float*)d_in[17];
    const float* ln_ego_g   = (const float*)d_in[18];
    const float* ln_ego_b   = (const float*)d_in[19];
    const float* ln_g       = (const float*)d_in[20];
    const float* ln_b       = (const float*)d_in[21];
    const float* ego_wih    = (const float*)d_in[22];
    const float* ego_whh    = (const float*)d_in[23];
    const float* ego_bih    = (const float*)d_in[24];
    const float* ego_bhh    = (const float*)d_in[25];
    const float* veh_wih    = (const float*)d_in[26];
    const float* veh_whh    = (const float*)d_in[27];
    const float* veh_bih    = (const float*)d_in[28];
    const float* veh_bhh    = (const float*)d_in[29];
    const float* out_ego_w  = (const float*)d_in[30];
    const float* out_ego_b  = (const float*)d_in[31];
    const float* out_w      = (const float*)d_in[32];
    const float* out_b      = (const float*)d_in[33];

    float* out = (float*)d_out;
    float* ws = (float*)d_ws;

    // workspace layout (floats)
    float* kv       = ws;                       // B*KVN*F
    float* qb       = kv + (size_t)B * KVN * F; // B*N1*F
    float* kb       = qb + (size_t)B * N1 * F;  // B*KVN*F
    float* vb       = kb + (size_t)B * KVN * F; // B*KVN*F
    float* xln      = vb + (size_t)B * KVN * F; // B*N1*F
    float* hbuf     = xln + (size_t)B * N1 * F;
    float* cbuf     = hbuf + (size_t)B * N1 * F;
    float* hist_pos = cbuf + (size_t)B * N1 * F;            // HH*B*N1*2
    float* pred_pos = hist_pos + (size_t)HH * B * N1 * 2;   // B*N1*NP*2
    float* wt       = pred_pos + (size_t)B * N1 * NP * 2;   // 4 * G4*F
    float* ego_wih_t = wt;
    float* ego_whh_t = wt + (size_t)G4 * F;
    float* veh_wih_t = wt + (size_t)2 * G4 * F;
    float* veh_whh_t = wt + (size_t)3 * G4 * F;

    // ---- init ----
    hipMemsetAsync(hbuf, 0, (size_t)B * N1 * F * sizeof(float), stream);
    hipMemsetAsync(cbuf, 0, (size_t)B * N1 * F * sizeof(float), stream);
    k_lane_tok<<<B * L, 64, 0, stream>>>(lane_input, lane_w1, lane_b1, lane_w2, lane_b2,
                                         lane_to_f, kv);
    k_hist_pos<<<(B * N1 + 255) / 256, 256, 0, stream>>>(input, init_pos, hist_pos, pred_pos);
    k_transpose_all<<<(4 * G4 * F + 255) / 256, 256, 0, stream>>>(ego_wih, ego_whh, veh_wih,
                                                                  veh_whh, wt);
    k_lane_kv<<<B * 8, 256, 0, stream>>>(kv, wk, wv, kb, vb);

    // ---- history ----
    for (int t = 0; t < HH; ++t) {
        k_tok_qkv<<<B * 4, 256, 0, stream>>>(input, hist_pos, hbuf, pred_pos,
                                             conv_w, conv_b, pos_w, pos_b,
                                             wq, wk, wv, kv, qb, kb, vb, 0, t);
        k_attn_proj_ln<<<B, 512, 0, stream>>>(qb, kb, vb, kv, mask_input, lane_mask, wo,
                                              ln_ego_g, ln_ego_b, ln_g, ln_b, xln);
        k_lstm_pred<<<N1 * 8, 512, 0, stream>>>(xln, ego_wih_t, ego_whh_t, ego_bih, ego_bhh,
                                                veh_wih_t, veh_whh_t, veh_bih, veh_bhh,
                                                hbuf, cbuf, out_ego_w, out_ego_b, out_w, out_b,
                                                pred_pos, out, 0, 0);
    }

    // ---- prediction ----
    for (int s = 0; s < LEN; ++s) {
        k_tok_qkv<<<B * 4, 256, 0, stream>>>(input, hist_pos, hbuf, pred_pos,
                                             conv_w, conv_b, pos_w, pos_b,
                                             wq, wk, wv, kv, qb, kb, vb, 1, 0);
        k_attn_proj_ln<<<B, 512, 0, stream>>>(qb, kb, vb, kv, mask_input, lane_mask, wo,
                                              ln_ego_g, ln_ego_b, ln_g, ln_b, xln);
        k_lstm_pred<<<N1 * 8, 512, 0, stream>>>(xln, ego_wih_t, ego_whh_t, ego_bih, ego_bhh,
                                                veh_wih_t, veh_whh_t, veh_bih, veh_bhh,
                                                hbuf, cbuf, out_ego_w, out_ego_b, out_w, out_b,
                                                pred_pos, out, 1, s);
    }
}

// Round 3
// 5338.585 us; speedup vs baseline: 1.6831x; 1.6831x over previous
//
#include <hip/hip_runtime.h>
#include <hip/hip_bf16.h>
#include <math.h>

// ---------------- constants (fixed by setup_inputs) ----------------
constexpr int B   = 128;   // batch
constexpr int N1  = 32;    // agents (1 ego + 31 veh)
constexpr int HH  = 20;    // history steps (T-2)
constexpr int L   = 64;    // lanes
constexpr int PTS = 10;    // points per lane
constexpr int F   = 128;   // feature size
constexpr int LF  = 64;    // lane feature
constexpr int NH  = 8;     // heads
constexpr int HD  = 16;    // head dim
constexpr int KVN = 96;    // kv tokens = 32 agents + 64 lanes
constexpr int G4  = 512;   // 4*F lstm gates
constexpr int NP  = 6;     // num preds
constexpr int P6  = 36;    // NP*6
constexpr int LEN = 30;    // len_pred

__device__ __forceinline__ float sigmoidf(float x) { return 1.f / (1.f + expf(-x)); }

// ---------------- one-time kernels ----------------

__global__ void k_lane_tok(const float* __restrict__ lane_input,
                           const float* __restrict__ w1, const float* __restrict__ b1,
                           const float* __restrict__ w2, const float* __restrict__ b2,
                           const float* __restrict__ to_f,
                           float* __restrict__ kvbuf) {
    int bl = blockIdx.x; int b = bl / L, l = bl % L;
    int tid = threadIdx.x; // 64 threads
    __shared__ float h1[PTS][LF];
    __shared__ float m[LF];
    const float* xin = lane_input + ((size_t)(b * L + l) * PTS) * 2;
    float w10 = w1[tid], w11 = w1[LF + tid], bb1 = b1[tid];
    for (int p = 0; p < PTS; ++p) {
        float v = xin[p * 2] * w10 + xin[p * 2 + 1] * w11 + bb1;
        h1[p][tid] = fmaxf(v, 0.f);
    }
    __syncthreads();
    float acc = 0.f;
    for (int p = 0; p < PTS; ++p) {
        float s = b2[tid];
        for (int h = 0; h < LF; ++h) s += h1[p][h] * w2[h * LF + tid];
        acc += fmaxf(s, 0.f);
    }
    m[tid] = acc * (1.f / PTS);
    __syncthreads();
    float* outp = kvbuf + ((size_t)(b * KVN) + 32 + l) * F;
    for (int f = tid; f < F; f += LF) {
        float s = 0.f;
        for (int j = 0; j < LF; ++j) s += m[j] * to_f[j * F + f];
        outp[f] = s;
    }
}

// lane K/V: project constant lane tokens once. 8 rows per block.
__global__ void k_lane_kv(const float* __restrict__ kvbuf,
                          const float* __restrict__ wk, const float* __restrict__ wv,
                          float* __restrict__ kb, float* __restrict__ vb) {
    int g = blockIdx.x & 7, b = blockIdx.x >> 3;
    int n0 = 32 + g * 8;
    int tid = threadIdx.x; // 256
    int j = tid & 127, rh = tid >> 7; // rh 0..1
    __shared__ float tok[8][F];
    for (int i = tid; i < 8 * F; i += 256) {
        int r = i >> 7, c = i & 127;
        tok[r][c] = kvbuf[((size_t)b * KVN + n0 + r) * F + c];
    }
    __syncthreads();
    float ak[4] = {0, 0, 0, 0}, av[4] = {0, 0, 0, 0};
    int r0 = rh * 4;
    for (int k2 = 0; k2 < F; ++k2) {
        float wkv = wk[k2 * F + j], wvv = wv[k2 * F + j];
#pragma unroll
        for (int r = 0; r < 4; ++r) {
            float x = tok[r0 + r][k2];
            ak[r] += x * wkv; av[r] += x * wvv;
        }
    }
#pragma unroll
    for (int r = 0; r < 4; ++r) {
        int n = n0 + r0 + r;
        kb[((size_t)b * KVN + n) * F + j] = ak[r];
        vb[((size_t)b * KVN + n) * F + j] = av[r];
    }
}

__global__ void k_hist_pos(const float* __restrict__ input,
                           const float* __restrict__ init_pos,
                           float* __restrict__ hist_pos,
                           float* __restrict__ pred_pos) {
    int idx = blockIdx.x * blockDim.x + threadIdx.x;
    if (idx >= B * N1) return;
    float px = init_pos[idx * 2], py = init_pos[idx * 2 + 1];
    int b = idx / N1, n = idx % N1;
    for (int t = 0; t < HH; ++t) {
        const float* ip = input + ((size_t)(t * B + b) * N1 + n) * 2;
        float dl = ip[0], yaw = ip[1];
        px += dl * cosf(yaw);
        py += dl * sinf(yaw);
        float* hp = hist_pos + ((size_t)(t * B + b) * N1 + n) * 2;
        hp[0] = px; hp[1] = py;
    }
#pragma unroll
    for (int p = 0; p < NP; ++p) {
        pred_pos[((size_t)idx * NP + p) * 2 + 0] = px;
        pred_pos[((size_t)idx * NP + p) * 2 + 1] = py;
    }
}

__global__ void k_transpose_all(const float* __restrict__ w0, const float* __restrict__ w1,
                                const float* __restrict__ w2, const float* __restrict__ w3,
                                float* __restrict__ wt) {
    int i = blockIdx.x * blockDim.x + threadIdx.x;
    if (i >= 4 * G4 * F) return;
    int m = i / (G4 * F), rem = i % (G4 * F);
    int j = rem / F, k2 = rem % F;
    const float* src = (m == 0) ? w0 : (m == 1) ? w1 : (m == 2) ? w2 : w3;
    wt[(size_t)m * G4 * F + (size_t)k2 * G4 + j] = src[rem];
}

// ---------------- per-step kernels ----------------

// Kernel A: build agent tokens + q/k/v projections. grid B*4, block 256, 8 rows/block.
__global__ void k_tok_qkv(const float* __restrict__ input, const float* __restrict__ hist_pos,
                          const float* __restrict__ h, const float* __restrict__ pred_pos,
                          const float* __restrict__ conv_w, const float* __restrict__ conv_b,
                          const float* __restrict__ pos_w, const float* __restrict__ pos_b,
                          const float* __restrict__ wq, const float* __restrict__ wk,
                          const float* __restrict__ wv,
                          float* __restrict__ kvbuf, float* __restrict__ qb,
                          float* __restrict__ kb, float* __restrict__ vb,
                          int mode, int t) {
    int g = blockIdx.x & 3, b = blockIdx.x >> 2;
    int n0 = g * 8;
    int tid = threadIdx.x;
    int j = tid & 127, rh = tid >> 7;
    __shared__ float tok[8][F];
    for (int i = tid; i < 8 * F; i += 256) {
        int r = i >> 7, c = i & 127;
        int n = n0 + r;
        float acc;
        if (mode == 0) {
            acc = conv_b[c];
#pragma unroll
            for (int kt = 0; kt < 3; ++kt) {
                const float* ip = input + ((size_t)((t + kt) * B + b) * N1 + n) * 2;
                acc += ip[0] * conv_w[(c * 2 + 0) * 3 + kt] + ip[1] * conv_w[(c * 2 + 1) * 3 + kt];
            }
            const float* hp = hist_pos + ((size_t)(t * B + b) * N1 + n) * 2;
            acc += hp[0] * pos_w[c] + hp[1] * pos_w[F + c] + pos_b[c];
        } else {
            const float* pp = pred_pos + ((size_t)(b * N1 + n)) * NP * 2;
            float mx = 0.f, my = 0.f;
#pragma unroll
            for (int p = 0; p < NP; ++p) { mx += pp[p * 2]; my += pp[p * 2 + 1]; }
            mx *= (1.f / NP); my *= (1.f / NP);
            acc = h[((size_t)b * N1 + n) * F + c] + mx * pos_w[c] + my * pos_w[F + c] + pos_b[c];
        }
        tok[r][c] = acc;
        kvbuf[((size_t)b * KVN + n) * F + c] = acc;
    }
    __syncthreads();
    float aq[4] = {0, 0, 0, 0}, ak[4] = {0, 0, 0, 0}, av[4] = {0, 0, 0, 0};
    int r0 = rh * 4;
    for (int k2 = 0; k2 < F; k2 += 2) {
        float wq0 = wq[k2 * F + j], wk0 = wk[k2 * F + j], wv0 = wv[k2 * F + j];
        float wq1 = wq[(k2 + 1) * F + j], wk1 = wk[(k2 + 1) * F + j], wv1 = wv[(k2 + 1) * F + j];
#pragma unroll
        for (int r = 0; r < 4; ++r) {
            float x0 = tok[r0 + r][k2], x1 = tok[r0 + r][k2 + 1];
            aq[r] += x0 * wq0 + x1 * wq1;
            ak[r] += x0 * wk0 + x1 * wk1;
            av[r] += x0 * wv0 + x1 * wv1;
        }
    }
#pragma unroll
    for (int r = 0; r < 4; ++r) {
        int n = n0 + r0 + r;
        qb[((size_t)b * N1 + n) * F + j]  = aq[r];
        kb[((size_t)b * KVN + n) * F + j] = ak[r];
        vb[((size_t)b * KVN + n) * F + j] = av[r];
    }
}

// Kernel B1: attention per (batch, head). grid B*NH = 1024 blocks, block 128.
__global__ void k_attn(const float* __restrict__ qb, const float* __restrict__ kb,
                       const float* __restrict__ vb,
                       const float* __restrict__ mask_in, const float* __restrict__ lane_mask,
                       float* __restrict__ ao) {
    int h = blockIdx.x & 7, b = blockIdx.x >> 3;
    int tid = threadIdx.x; // 128
    __shared__ float qh[N1][HD];       // broadcast reads only
    __shared__ float kh[KVN][HD + 1];  // pad -> odd stride, conflict-free
    __shared__ float vh[KVN][HD + 1];
    __shared__ float mk[KVN];
    __shared__ float sc[N1][KVN + 1];
    for (int i = tid; i < N1 * HD; i += 128) {
        int qr = i >> 4, d = i & 15;
        qh[qr][d] = qb[((size_t)b * N1 + qr) * F + h * HD + d];
    }
    for (int i = tid; i < KVN * HD; i += 128) {
        int kc = i >> 4, d = i & 15;
        kh[kc][d] = kb[((size_t)b * KVN + kc) * F + h * HD + d];
        vh[kc][d] = vb[((size_t)b * KVN + kc) * F + h * HD + d];
    }
    if (tid < KVN)
        mk[tid] = (tid < N1) ? mask_in[b * N1 + tid] : lane_mask[b * L + (tid - N1)];
    __syncthreads();
    // scores
    for (int i = tid; i < N1 * KVN; i += 128) {
        int qr = i / KVN, kc = i % KVN;
        float acc = 0.f;
#pragma unroll
        for (int d = 0; d < HD; ++d) acc += qh[qr][d] * kh[kc][d];
        sc[qr][kc] = (mk[kc] > 0.f) ? acc * 0.25f : -1e9f;
    }
    __syncthreads();
    // softmax per row
    if (tid < N1) {
        float mx = -1e30f;
        for (int kc = 0; kc < KVN; ++kc) mx = fmaxf(mx, sc[tid][kc]);
        float sum = 0.f;
        for (int kc = 0; kc < KVN; ++kc) { float e = expf(sc[tid][kc] - mx); sc[tid][kc] = e; sum += e; }
        float inv = 1.f / sum;
        for (int kc = 0; kc < KVN; ++kc) sc[tid][kc] *= inv;
    }
    __syncthreads();
    // PV
    for (int i = tid; i < N1 * HD; i += 128) {
        int qr = i >> 4, d = i & 15;
        float acc = 0.f;
        for (int kc = 0; kc < KVN; ++kc) acc += sc[qr][kc] * vh[kc][d];
        ao[((size_t)b * N1 + qr) * F + h * HD + d] = acc;
    }
}

// Kernel B2: out-proj + residual + layernorm. grid B*4, block 256, 8 rows/block.
__global__ void k_proj_ln(const float* __restrict__ ao, const float* __restrict__ kvbuf,
                          const float* __restrict__ wo,
                          const float* __restrict__ ln_ego_g, const float* __restrict__ ln_ego_b,
                          const float* __restrict__ ln_g, const float* __restrict__ ln_b,
                          float* __restrict__ xln) {
    int gq = blockIdx.x & 3, b = blockIdx.x >> 2;
    int n0 = gq * 8;
    int tid = threadIdx.x; // 256
    int j = tid & 127, rh = tid >> 7;
    __shared__ float arow[8][F];
    __shared__ float xb[8][F + 1];
    __shared__ float st[8][2];
    for (int i = tid; i < 8 * F; i += 256) {
        int r = i >> 7, c = i & 127;
        arow[r][c] = ao[((size_t)b * N1 + n0 + r) * F + c];
    }
    __syncthreads();
    float acc[4] = {0, 0, 0, 0};
    int r0 = rh * 4;
    for (int k2 = 0; k2 < F; k2 += 2) {
        float w0 = wo[k2 * F + j], w1 = wo[(k2 + 1) * F + j];
#pragma unroll
        for (int r = 0; r < 4; ++r)
            acc[r] += arow[r0 + r][k2] * w0 + arow[r0 + r][k2 + 1] * w1;
    }
#pragma unroll
    for (int r = 0; r < 4; ++r)
        xb[r0 + r][j] = kvbuf[((size_t)b * KVN + n0 + r0 + r) * F + j] + acc[r];
    __syncthreads();
    if (tid < 8) {
        float s1 = 0.f, s2 = 0.f;
        for (int c = 0; c < F; ++c) { float x = xb[tid][c]; s1 += x; s2 += x * x; }
        float mean = s1 * (1.f / F);
        float var = s2 * (1.f / F) - mean * mean;
        st[tid][0] = mean; st[tid][1] = rsqrtf(var + 1e-5f);
    }
    __syncthreads();
    for (int i = tid; i < 8 * F; i += 256) {
        int r = i >> 7, c = i & 127;
        int n = n0 + r;
        const float* g  = (n == 0) ? ln_ego_g : ln_g;
        const float* bb = (n == 0) ? ln_ego_b : ln_b;
        xln[((size_t)b * N1 + n) * F + c] = (xb[r][c] - st[r][0]) * st[r][1] * g[c] + bb[c];
    }
}

// Kernel C: LSTM cell (16 batch rows/block) + (pred mode) output head + pos update + y.
// grid N1*8 = 256 blocks, block 512.
__global__ void k_lstm_pred(const float* __restrict__ xln,
                            const float* __restrict__ ego_wih_t, const float* __restrict__ ego_whh_t,
                            const float* __restrict__ ego_bih, const float* __restrict__ ego_bhh,
                            const float* __restrict__ veh_wih_t, const float* __restrict__ veh_whh_t,
                            const float* __restrict__ veh_bih, const float* __restrict__ veh_bhh,
                            float* __restrict__ h, float* __restrict__ c,
                            const float* __restrict__ out_ego_w, const float* __restrict__ out_ego_b,
                            const float* __restrict__ out_w, const float* __restrict__ out_b,
                            float* __restrict__ pred_pos, float* __restrict__ out,
                            int mode, int step) {
    int n = blockIdx.x >> 3, bg = blockIdx.x & 7;
    int b0 = bg * 16;
    int j = threadIdx.x; // 512
    const float *wih, *whh, *bih, *bhh;
    if (n == 0) { wih = ego_wih_t; whh = ego_whh_t; bih = ego_bih; bhh = ego_bhh; }
    else        { wih = veh_wih_t; whh = veh_whh_t; bih = veh_bih; bhh = veh_bhh; }
    __shared__ float xr[16][F];  // later reused to hold h2
    __shared__ float hr2[16][F];
    __shared__ float gs[16][G4];
    for (int i = j; i < 16 * F; i += 512) {
        int r = i >> 7, k2 = i & 127;
        size_t bn = (size_t)(b0 + r) * N1 + n;
        xr[r][k2]  = xln[bn * F + k2];
        hr2[r][k2] = h[bn * F + k2];
    }
    __syncthreads();
    float acc[16];
    float bsum = bih[j] + bhh[j];
#pragma unroll
    for (int r = 0; r < 16; ++r) acc[r] = bsum;
    for (int k2 = 0; k2 < F; k2 += 4) {
        float wa0 = wih[(size_t)(k2    ) * G4 + j], wb0 = whh[(size_t)(k2    ) * G4 + j];
        float wa1 = wih[(size_t)(k2 + 1) * G4 + j], wb1 = whh[(size_t)(k2 + 1) * G4 + j];
        float wa2 = wih[(size_t)(k2 + 2) * G4 + j], wb2 = whh[(size_t)(k2 + 2) * G4 + j];
        float wa3 = wih[(size_t)(k2 + 3) * G4 + j], wb3 = whh[(size_t)(k2 + 3) * G4 + j];
#pragma unroll
        for (int r = 0; r < 16; ++r) {
            // contiguous 4-wide LDS reads -> ds_read_b128
            float x0 = xr[r][k2], x1 = xr[r][k2 + 1], x2 = xr[r][k2 + 2], x3 = xr[r][k2 + 3];
            float h0 = hr2[r][k2], h1 = hr2[r][k2 + 1], h2v = hr2[r][k2 + 2], h3 = hr2[r][k2 + 3];
            acc[r] += x0 * wa0 + x1 * wa1 + x2 * wa2 + x3 * wa3
                    + h0 * wb0 + h1 * wb1 + h2v * wb2 + h3 * wb3;
        }
    }
#pragma unroll
    for (int r = 0; r < 16; ++r) gs[r][j] = acc[r];
    __syncthreads();
    for (int i = j; i < 16 * F; i += 512) {
        int r = i >> 7, f = i & 127;
        size_t bn = (size_t)(b0 + r) * N1 + n;
        float ig = gs[r][f], fg = gs[r][F + f], gg = gs[r][2 * F + f], og = gs[r][3 * F + f];
        float cold = c[bn * F + f];
        float c2 = sigmoidf(fg) * cold + sigmoidf(ig) * tanhf(gg);
        float h2 = sigmoidf(og) * tanhf(c2);
        c[bn * F + f] = c2;
        h[bn * F + f] = h2;
        xr[r][f] = h2;   // stash for pred head
    }
    if (mode == 1) {
        const float* W  = (n == 0) ? out_ego_w : out_w;
        const float* bb = (n == 0) ? out_ego_b : out_b;
        __syncthreads();
        for (int i = j; i < 16 * P6; i += 512) {
            int r = i / P6, jj = i % P6;
            float a = bb[jj];
            for (int k2 = 0; k2 < F; ++k2) a += xr[r][k2] * W[k2 * P6 + jj];
            gs[r][jj] = a; // reuse gs as o36 store
        }
        __syncthreads();
        if (j < 16 * NP) {
            int r = j / NP, p = j % NP;
            size_t bn = (size_t)(b0 + r) * N1 + n;
            float dl = gs[r][p * 6 + 0], yaw = gs[r][p * 6 + 1];
            float* pp = pred_pos + (bn * NP + p) * 2;
            float px = pp[0] + dl * cosf(yaw);
            float py = pp[1] + dl * sinf(yaw);
            pp[0] = px; pp[1] = py;
            float* y = out + (size_t)step * B * N1 * P6 + (bn * NP + p) * 6;
            y[0] = px; y[1] = py;
            y[2] = gs[r][p * 6 + 2]; y[3] = gs[r][p * 6 + 3];
            y[4] = gs[r][p * 6 + 4]; y[5] = gs[r][p * 6 + 5];
        }
    }
}

// ---------------- launcher ----------------
extern "C" void kernel_launch(void* const* d_in, const int* in_sizes, int n_in,
                              void* d_out, int out_size, void* d_ws, size_t ws_size,
                              hipStream_t stream) {
    const float* input      = (const float*)d_in[0];
    const float* init_pos   = (const float*)d_in[1];
    const float* lane_input = (const float*)d_in[2];
    const float* mask_input = (const float*)d_in[3];
    const float* lane_mask  = (const float*)d_in[4];
    const float* conv_w     = (const float*)d_in[5];
    const float* conv_b     = (const float*)d_in[6];
    const float* pos_w      = (const float*)d_in[7];
    const float* pos_b      = (const float*)d_in[8];
    const float* lane_w1    = (const float*)d_in[9];
    const float* lane_b1    = (const float*)d_in[10];
    const float* lane_w2    = (const float*)d_in[11];
    const float* lane_b2    = (const float*)d_in[12];
    const float* lane_to_f  = (const float*)d_in[13];
    const float* wq         = (const float*)d_in[14];
    const float* wk         = (const float*)d_in[15];
    const float* wv         = (const float*)d_in[16];
    const float* wo         = (const float*)d_in[17];
    const float* ln_ego_g   = (const float*)d_in[18];
    const float* ln_ego_b   = (const float*)d_in[19];
    const float* ln_g       = (const float*)d_in[20];
    const float* ln_b       = (const float*)d_in[21];
    const float* ego_wih    = (const float*)d_in[22];
    const float* ego_whh    = (const float*)d_in[23];
    const float* ego_bih    = (const float*)d_in[24];
    const float* ego_bhh    = (const float*)d_in[25];
    const float* veh_wih    = (const float*)d_in[26];
    const float* veh_whh    = (const float*)d_in[27];
    const float* veh_bih    = (const float*)d_in[28];
    const float* veh_bhh    = (const float*)d_in[29];
    const float* out_ego_w  = (const float*)d_in[30];
    const float* out_ego_b  = (const float*)d_in[31];
    const float* out_w      = (const float*)d_in[32];
    const float* out_b      = (const float*)d_in[33];

    float* out = (float*)d_out;
    float* ws = (float*)d_ws;

    // workspace layout (floats)
    float* kv       = ws;                       // B*KVN*F
    float* qb       = kv + (size_t)B * KVN * F; // B*N1*F
    float* kb       = qb + (size_t)B * N1 * F;  // B*KVN*F
    float* vb       = kb + (size_t)B * KVN * F; // B*KVN*F
    float* ao       = vb + (size_t)B * KVN * F; // B*N1*F
    float* xln      = ao + (size_t)B * N1 * F;  // B*N1*F
    float* hbuf     = xln + (size_t)B * N1 * F;
    float* cbuf     = hbuf + (size_t)B * N1 * F;
    float* hist_pos = cbuf + (size_t)B * N1 * F;            // HH*B*N1*2
    float* pred_pos = hist_pos + (size_t)HH * B * N1 * 2;   // B*N1*NP*2
    float* wt       = pred_pos + (size_t)B * N1 * NP * 2;   // 4 * G4*F
    float* ego_wih_t = wt;
    float* ego_whh_t = wt + (size_t)G4 * F;
    float* veh_wih_t = wt + (size_t)2 * G4 * F;
    float* veh_whh_t = wt + (size_t)3 * G4 * F;

    // ---- init ----
    hipMemsetAsync(hbuf, 0, (size_t)B * N1 * F * sizeof(float), stream);
    hipMemsetAsync(cbuf, 0, (size_t)B * N1 * F * sizeof(float), stream);
    k_lane_tok<<<B * L, 64, 0, stream>>>(lane_input, lane_w1, lane_b1, lane_w2, lane_b2,
                                         lane_to_f, kv);
    k_hist_pos<<<(B * N1 + 255) / 256, 256, 0, stream>>>(input, init_pos, hist_pos, pred_pos);
    k_transpose_all<<<(4 * G4 * F + 255) / 256, 256, 0, stream>>>(ego_wih, ego_whh, veh_wih,
                                                                  veh_whh, wt);
    k_lane_kv<<<B * 8, 256, 0, stream>>>(kv, wk, wv, kb, vb);

    // ---- history ----
    for (int t = 0; t < HH; ++t) {
        k_tok_qkv<<<B * 4, 256, 0, stream>>>(input, hist_pos, hbuf, pred_pos,
                                             conv_w, conv_b, pos_w, pos_b,
                                             wq, wk, wv, kv, qb, kb, vb, 0, t);
        k_attn<<<B * NH, 128, 0, stream>>>(qb, kb, vb, mask_input, lane_mask, ao);
        k_proj_ln<<<B * 4, 256, 0, stream>>>(ao, kv, wo, ln_ego_g, ln_ego_b, ln_g, ln_b, xln);
        k_lstm_pred<<<N1 * 8, 512, 0, stream>>>(xln, ego_wih_t, ego_whh_t, ego_bih, ego_bhh,
                                                veh_wih_t, veh_whh_t, veh_bih, veh_bhh,
                                                hbuf, cbuf, out_ego_w, out_ego_b, out_w, out_b,
                                                pred_pos, out, 0, 0);
    }

    // ---- prediction ----
    for (int s = 0; s < LEN; ++s) {
        k_tok_qkv<<<B * 4, 256, 0, stream>>>(input, hist_pos, hbuf, pred_pos,
                                             conv_w, conv_b, pos_w, pos_b,
                                             wq, wk, wv, kv, qb, kb, vb, 1, 0);
        k_attn<<<B * NH, 128, 0, stream>>>(qb, kb, vb, mask_input, lane_mask, ao);
        k_proj_ln<<<B * 4, 256, 0, stream>>>(ao, kv, wo, ln_ego_g, ln_ego_b, ln_g, ln_b, xln);
        k_lstm_pred<<<N1 * 8, 512, 0, stream>>>(xln, ego_wih_t, ego_whh_t, ego_bih, ego_bhh,
                                                veh_wih_t, veh_whh_t, veh_bih, veh_bhh,
                                                hbuf, cbuf, out_ego_w, out_ego_b, out_w, out_b,
                                                pred_pos, out, 1, s);
    }
}